// Round 1
// baseline (982.274 us; speedup 1.0000x reference)
//
#include <hip/hip_runtime.h>
#include <math.h>

#define B_SZ   16384
#define D_DIM  256
#define E_NUM  8
#define O_DIM  128
#define CTXW   32
#define H1     64

// out layout (all f32):
//  [0 .. 2097151]          predictions [B,128]
//  [2097152 .. 2129919]    routing_w   [B,2]
//  [2129920 .. 2162687]    top_idx     [B,2] (as float)
//  [2162688 .. 2162695]    new_pulls   [8]
//  [2162696 .. 2162703]    new_avg     [8]
//  [2162704 .. 2162711]    new_ema     [8]
#define OFF_RW   2097152
#define OFF_IDX  2129920
#define OFF_NP   2162688
#define OFF_NA   2162696
#define OFF_NE   2162704

// ws layout (f32): [0..7] counts, [8..15] reward sums, [16..23] routing-w sums

__global__ void init_ws_k(float* ws) {
    int i = threadIdx.x;
    if (i < 24) ws[i] = 0.0f;
}

__global__ __launch_bounds__(256) void router_main(
    const float* __restrict__ x, const float* __restrict__ targets,
    const float* __restrict__ W1, const float* __restrict__ b1,
    const float* __restrict__ W2, const float* __restrict__ b2,
    const float* __restrict__ S1, const float* __restrict__ sb1,
    const float* __restrict__ S2, const float* __restrict__ sb2,
    const float* __restrict__ We, const float* __restrict__ be,
    const float* __restrict__ expert_rewards,
    const int* __restrict__ expert_pulls,
    const int* __restrict__ total_sel,
    float* __restrict__ out, float* __restrict__ ws)
{
    const int wave = threadIdx.x >> 6;   // 0..3
    const int lane = threadIdx.x & 63;
    const int row  = blockIdx.x * 4 + wave;

    __shared__ float  xs[4][D_DIM];
    __shared__ double hs[4][H1];
    __shared__ double cs[4][CTXW];
    __shared__ double tsh[4][CTXW];
    __shared__ double ucb_sh[4][E_NUM];

    // ---- stage x row into LDS (coalesced float4) ----
    const float* xr = x + (size_t)row * D_DIM;
    ((float4*)xs[wave])[lane] = ((const float4*)xr)[lane];
    __syncthreads();

    // ---- h = relu(x @ W1 + b1), one unit per lane, f64 ----
    {
        double acc = (double)b1[lane];
        for (int d = 0; d < D_DIM; ++d)
            acc = fma((double)xs[wave][d], (double)W1[d * H1 + lane], acc);
        hs[wave][lane] = acc > 0.0 ? acc : 0.0;
    }
    __syncthreads();

    // ---- context = tanh(h @ W2 + b2), lanes 0..31, f64 ----
    if (lane < CTXW) {
        double a = (double)b2[lane];
        for (int k = 0; k < H1; ++k)
            a = fma(hs[wave][k], (double)W2[k * CTXW + lane], a);
        cs[wave][lane] = tanh(a);
    }
    __syncthreads();

    // ---- t = relu(context @ S1 + sb1), lanes 0..31, f64 ----
    if (lane < CTXW) {
        double a = (double)sb1[lane];
        for (int k = 0; k < CTXW; ++k)
            a = fma(cs[wave][k], (double)S1[k * CTXW + lane], a);
        tsh[wave][lane] = a > 0.0 ? a : 0.0;
    }
    __syncthreads();

    // ---- scores + UCB constants, lanes 0..7, f64 ----
    if (lane < E_NUM) {
        double a = (double)sb2[lane];
        for (int k = 0; k < CTXW; ++k)
            a = fma(tsh[wave][k], (double)S2[k * E_NUM + lane], a);
        double pf = (double)expert_pulls[lane];
        double sp = pf < 1.0 ? 1.0 : pf;
        double explo = 0.1 * sqrt(log((double)(*total_sel)) / sp);
        double avg   = pf > 0.0 ? (double)expert_rewards[lane] / sp : 0.0;
        ucb_sh[wave][lane] = a + avg + explo;
    }
    __syncthreads();

    // ---- top-2 (stable: lower index wins ties), redundantly on all lanes ----
    double u[E_NUM];
    #pragma unroll
    for (int e = 0; e < E_NUM; ++e) u[e] = ucb_sh[wave][e];
    int i0 = 0; double v0 = u[0];
    #pragma unroll
    for (int e = 1; e < E_NUM; ++e) if (u[e] > v0) { v0 = u[e]; i0 = e; }
    int i1 = (i0 == 0) ? 1 : 0; double v1 = u[i1];
    #pragma unroll
    for (int e = 0; e < E_NUM; ++e) {
        if (e != i0 && e != ((i0 == 0) ? 1 : 0) && u[e] > v1) { v1 = u[e]; i1 = e; }
    }
    // softmax over [v0, v1], v0 >= v1
    double exd = exp(v1 - v0);
    double w0d = 1.0 / (1.0 + exd);
    double w1d = exd / (1.0 + exd);

    if (lane == 0) {
        out[OFF_RW  + row * 2]     = (float)w0d;
        out[OFF_RW  + row * 2 + 1] = (float)w1d;
        out[OFF_IDX + row * 2]     = (float)i0;
        out[OFF_IDX + row * 2 + 1] = (float)i1;
    }

    // ---- expert matvecs (f32): sel[o] = x @ We[e][:,o] + be[e][o] ----
    const float* Wa = We + (size_t)i0 * D_DIM * O_DIM;
    const float* Wb = We + (size_t)i1 * D_DIM * O_DIM;
    float s0a = 0.f, s0b = 0.f, s1a = 0.f, s1b = 0.f;
    for (int d = 0; d < D_DIM; ++d) {
        float xd = xs[wave][d];
        const float* ra = Wa + d * O_DIM;
        const float* rb = Wb + d * O_DIM;
        s0a = fmaf(xd, ra[lane],      s0a);
        s0b = fmaf(xd, ra[lane + 64], s0b);
        s1a = fmaf(xd, rb[lane],      s1a);
        s1b = fmaf(xd, rb[lane + 64], s1b);
    }
    s0a += be[i0 * O_DIM + lane]; s0b += be[i0 * O_DIM + lane + 64];
    s1a += be[i1 * O_DIM + lane]; s1b += be[i1 * O_DIM + lane + 64];

    float w0f = (float)w0d, w1f = (float)w1d;
    out[(size_t)row * O_DIM + lane]      = w0f * s0a + w1f * s1a;
    out[(size_t)row * O_DIM + lane + 64] = w0f * s0b + w1f * s1b;

    // ---- per-expert MSE losses -> rewards ----
    float t0 = targets[(size_t)row * O_DIM + lane];
    float t1 = targets[(size_t)row * O_DIM + lane + 64];
    float d0a = s0a - t0, d0b = s0b - t1, d1a = s1a - t0, d1b = s1b - t1;
    float p0 = d0a * d0a + d0b * d0b;
    float p1 = d1a * d1a + d1b * d1b;
    #pragma unroll
    for (int off = 32; off > 0; off >>= 1) {
        p0 += __shfl_down(p0, off, 64);
        p1 += __shfl_down(p1, off, 64);
    }
    if (lane == 0) {
        float r0 = -(p0 * (1.0f / 128.0f));
        float r1 = -(p1 * (1.0f / 128.0f));
        atomicAdd(&ws[i0], 1.0f);
        atomicAdd(&ws[i1], 1.0f);
        atomicAdd(&ws[8 + i0], r0);
        atomicAdd(&ws[8 + i1], r1);
        atomicAdd(&ws[16 + i0], w0f);
        atomicAdd(&ws[16 + i1], w1f);
    }
}

__global__ void finalize_k(const float* __restrict__ expert_rewards,
                           const float* __restrict__ routing_ema,
                           const int* __restrict__ expert_pulls,
                           const float* __restrict__ ws,
                           float* __restrict__ out)
{
    int e = threadIdx.x;
    if (e < E_NUM) {
        double pf   = (double)expert_pulls[e];
        double npl  = pf + (double)ws[e];
        double ntr  = (double)expert_rewards[e] + (double)ws[8 + e];
        double sp   = npl < 1.0 ? 1.0 : npl;
        double navg = npl > 0.0 ? ntr / sp : 0.0;
        double prob = (double)ws[16 + e] / (double)B_SZ;
        double nema = 0.99 * (double)routing_ema[e] + 0.01 * prob;
        out[OFF_NP + e] = (float)npl;
        out[OFF_NA + e] = (float)navg;
        out[OFF_NE + e] = (float)nema;
    }
}

extern "C" void kernel_launch(void* const* d_in, const int* in_sizes, int n_in,
                              void* d_out, int out_size, void* d_ws, size_t ws_size,
                              hipStream_t stream) {
    const float* x    = (const float*)d_in[0];
    const float* tgt  = (const float*)d_in[1];
    const float* W1   = (const float*)d_in[2];
    const float* b1   = (const float*)d_in[3];
    const float* W2   = (const float*)d_in[4];
    const float* b2   = (const float*)d_in[5];
    const float* S1   = (const float*)d_in[6];
    const float* sb1  = (const float*)d_in[7];
    const float* S2   = (const float*)d_in[8];
    const float* sb2  = (const float*)d_in[9];
    const float* We   = (const float*)d_in[10];
    const float* be   = (const float*)d_in[11];
    const float* erw  = (const float*)d_in[12];
    const float* ema  = (const float*)d_in[13];
    const int*   pulls = (const int*)d_in[14];
    const int*   tsel  = (const int*)d_in[15];
    float* out = (float*)d_out;
    float* ws  = (float*)d_ws;

    init_ws_k<<<1, 32, 0, stream>>>(ws);
    router_main<<<B_SZ / 4, 256, 0, stream>>>(
        x, tgt, W1, b1, W2, b2, S1, sb1, S2, sb2, We, be,
        erw, pulls, tsel, out, ws);
    finalize_k<<<1, 64, 0, stream>>>(erw, ema, pulls, ws, out);
}

// Round 4
// 225.168 us; speedup vs baseline: 4.3624x; 4.3624x over previous
//
#include <hip/hip_runtime.h>
#include <math.h>

#define B_SZ   16384
#define D_DIM  256
#define E_NUM  8
#define O_DIM  128
#define CTXW   32
#define H1     64

// out layout (f32):
#define OFF_RW   2097152
#define OFF_IDX  2129920
#define OFF_NP   2162688
#define OFF_NA   2162696
#define OFF_NE   2162704

// ws layout:
//  int  wsi[0..7]                 : per-expert counters (list cursors)
//  f32  wsf[256 + copy*24 + j]    : 64 stat copies; j: 0..7 cnt, 8..15 rsum, 16..23 wsum
//  int  wsi[2048 + e*16384 + i]   : per-expert row lists, entry = row*2 + slot
#define WS_STATS 256
#define WS_LIST  2048

// ---------------- K0: zero predictions + counters + stats ----------------
__global__ __launch_bounds__(256) void zero_k(float* out, float* ws) {
    int idx = blockIdx.x * 256 + threadIdx.x;
    if (idx < 524288) ((float4*)out)[idx] = make_float4(0.f, 0.f, 0.f, 0.f);
    if (idx < 512)    ((float4*)ws)[idx]  = make_float4(0.f, 0.f, 0.f, 0.f);
}

// ---------------- K1: encoder + scorer + UCB + top2 + list build (f64) ----------------
__global__ __launch_bounds__(256) void score_k(
    const float* __restrict__ x,
    const float* __restrict__ W1, const float* __restrict__ b1,
    const float* __restrict__ W2, const float* __restrict__ b2,
    const float* __restrict__ S1, const float* __restrict__ sb1,
    const float* __restrict__ S2, const float* __restrict__ sb2,
    const float* __restrict__ er, const int* __restrict__ pulls,
    const int* __restrict__ tsel,
    float* __restrict__ out, int* __restrict__ wsi)
{
    __shared__ float  xs[16][D_DIM];
    __shared__ double hs[16][H1];
    __shared__ double cs[16][CTXW];
    __shared__ double tss[16][CTXW];
    __shared__ double ucb[16][E_NUM];
    __shared__ int    se[32];

    const int t = threadIdx.x, lane = t & 63, wv = t >> 6;
    const int row0 = blockIdx.x * 16;

    // stage 16 rows of x
    const float4* xsrc = (const float4*)(x + (size_t)row0 * D_DIM);
    #pragma unroll
    for (int i = 0; i < 4; ++i)
        ((float4*)xs)[t + i * 256] = xsrc[t + i * 256];
    __syncthreads();

    // ---- h = relu(x@W1+b1): lane = unit, 4 rows per wave, 2 accs/row ----
    const int rb = wv * 4;
    {
        double a00 = (double)b1[lane], a01 = 0.0;
        double a10 = a00, a11 = 0.0;
        double a20 = a00, a21 = 0.0;
        double a30 = a00, a31 = 0.0;
        #pragma unroll 4
        for (int d = 0; d < D_DIM; d += 2) {
            float2 p0 = *(const float2*)&xs[rb + 0][d];
            float2 p1 = *(const float2*)&xs[rb + 1][d];
            float2 p2 = *(const float2*)&xs[rb + 2][d];
            float2 p3 = *(const float2*)&xs[rb + 3][d];
            double wa = (double)W1[d * H1 + lane];
            double wb = (double)W1[(d + 1) * H1 + lane];
            a00 = fma((double)p0.x, wa, a00); a01 = fma((double)p0.y, wb, a01);
            a10 = fma((double)p1.x, wa, a10); a11 = fma((double)p1.y, wb, a11);
            a20 = fma((double)p2.x, wa, a20); a21 = fma((double)p2.y, wb, a21);
            a30 = fma((double)p3.x, wa, a30); a31 = fma((double)p3.y, wb, a31);
        }
        double h0 = a00 + a01, h1 = a10 + a11, h2 = a20 + a21, h3 = a30 + a31;
        hs[rb + 0][lane] = h0 > 0.0 ? h0 : 0.0;
        hs[rb + 1][lane] = h1 > 0.0 ? h1 : 0.0;
        hs[rb + 2][lane] = h2 > 0.0 ? h2 : 0.0;
        hs[rb + 3][lane] = h3 > 0.0 ? h3 : 0.0;
    }
    __syncthreads();

    // ---- context = tanh(h@W2+b2): unit = lane&31, half handles 2 rows ----
    {
        const int unit = lane & 31, half = lane >> 5;
        const int ra = rb + half * 2;
        double c0 = (double)b2[unit], c1 = c0;
        #pragma unroll 4
        for (int k = 0; k < H1; ++k) {
            double w2 = (double)W2[k * CTXW + unit];
            c0 = fma(hs[ra][k], w2, c0);
            c1 = fma(hs[ra + 1][k], w2, c1);
        }
        cs[ra][unit] = tanh(c0);
        cs[ra + 1][unit] = tanh(c1);
    }
    __syncthreads();

    // ---- tmid = relu(context@S1+sb1) ----
    {
        const int unit = lane & 31, half = lane >> 5;
        const int ra = rb + half * 2;
        double a0 = (double)sb1[unit], a1 = a0;
        #pragma unroll 4
        for (int k = 0; k < CTXW; ++k) {
            double s1 = (double)S1[k * CTXW + unit];
            a0 = fma(cs[ra][k], s1, a0);
            a1 = fma(cs[ra + 1][k], s1, a1);
        }
        tss[ra][unit]     = a0 > 0.0 ? a0 : 0.0;
        tss[ra + 1][unit] = a1 > 0.0 ? a1 : 0.0;
    }
    __syncthreads();

    // ---- scores + UCB: lanes<32, e = lane&7, row = rb + (lane>>3) ----
    if (lane < 32) {
        const int e = lane & 7, r = rb + (lane >> 3);
        double a = (double)sb2[e];
        #pragma unroll 4
        for (int k = 0; k < CTXW; ++k)
            a = fma(tss[r][k], (double)S2[k * E_NUM + e], a);
        double pf = (double)pulls[e];
        double sp = pf < 1.0 ? 1.0 : pf;
        double explo = 0.1 * sqrt(log((double)(*tsel)) / sp);
        double avg = pf > 0.0 ? (double)er[e] / sp : 0.0;
        ucb[r][e] = a + avg + explo;
    }
    __syncthreads();

    // ---- top2 + softmax + emit: threads 0..15, one row each ----
    if (t < 16) {
        double u[E_NUM];
        #pragma unroll
        for (int e = 0; e < E_NUM; ++e) u[e] = ucb[t][e];
        int i0 = 0; double v0 = u[0];
        #pragma unroll
        for (int e = 1; e < E_NUM; ++e) if (u[e] > v0) { v0 = u[e]; i0 = e; }
        int i1 = -1; double v1 = -1.0e300;
        #pragma unroll
        for (int e = 0; e < E_NUM; ++e) {
            if (e == i0) continue;
            if (u[e] > v1) { v1 = u[e]; i1 = e; }
        }
        double exd = exp(v1 - v0);
        double w0 = 1.0 / (1.0 + exd), w1 = exd / (1.0 + exd);
        int row = row0 + t;
        out[OFF_RW  + row * 2]     = (float)w0;
        out[OFF_RW  + row * 2 + 1] = (float)w1;
        out[OFF_IDX + row * 2]     = (float)i0;
        out[OFF_IDX + row * 2 + 1] = (float)i1;
        se[t * 2]     = i0;
        se[t * 2 + 1] = i1;
    }
    __syncthreads();

    // ---- block-aggregated list append: threads 0..7 (one per expert) ----
    if (t < E_NUM) {
        int cntl = 0;
        #pragma unroll
        for (int j = 0; j < 32; ++j) cntl += (se[j] == t);
        if (cntl) {
            int base = atomicAdd(&wsi[t], cntl);
            int k = 0;
            for (int j = 0; j < 32; ++j)
                if (se[j] == t)
                    wsi[WS_LIST + t * B_SZ + base + (k++)] = (row0 + (j >> 1)) * 2 + (j & 1);
        }
    }
}

// ---------------- K2: grouped expert GEMM + losses + stats ----------------
__global__ __launch_bounds__(256) void expert_k(
    const float* __restrict__ x, const float* __restrict__ tgt,
    const float* __restrict__ We, const float* __restrict__ be,
    float* out, int* __restrict__ wsi, float* __restrict__ wsf)
{
    const int e = blockIdx.x >> 8, chunk = blockIdx.x & 255;
    const int cnt = wsi[e];
    const int base = chunk * 64;
    if (base >= cnt) return;

    __shared__ float xsl[64][68];
    __shared__ float wes[64][O_DIM];
    __shared__ int   rowid[64];
    __shared__ float wsl[64];
    __shared__ float be_sh[O_DIM];

    const int t = threadIdx.x;
    if (t < 64) {
        int en = (base + t < cnt) ? wsi[WS_LIST + e * B_SZ + base + t] : -1;
        rowid[t] = (en >= 0) ? (en >> 1) : -1;
        wsl[t]   = (en >= 0) ? out[OFF_RW + en] : 0.f;
    }
    if (t < O_DIM) be_sh[t] = be[e * O_DIM + t];

    float acc[8][4];
    #pragma unroll
    for (int r = 0; r < 8; ++r)
        #pragma unroll
        for (int j = 0; j < 4; ++j) acc[r][j] = 0.f;

    const int tx = t & 31, ty = t >> 5;
    const int o4 = tx * 4;

    for (int k0 = 0; k0 < 4; ++k0) {
        __syncthreads();
        // stage We chunk [64 k][128 o] — contiguous 32 KB
        const float4* wsrc = (const float4*)(We + ((size_t)e * D_DIM + k0 * 64) * O_DIM);
        #pragma unroll
        for (int i = 0; i < 8; ++i)
            ((float4*)wes)[t + i * 256] = wsrc[t + i * 256];
        // stage x rows [64 r][64 k]
        {
            int r = t >> 2, seg = t & 3;
            int rr = rowid[r] < 0 ? 0 : rowid[r];
            const float* xsr = x + (size_t)rr * D_DIM + k0 * 64 + seg * 16;
            #pragma unroll
            for (int j = 0; j < 4; ++j)
                *(float4*)&xsl[r][seg * 16 + j * 4] = *(const float4*)(xsr + j * 4);
        }
        __syncthreads();
        // compute
        #pragma unroll 4
        for (int kq = 0; kq < 16; ++kq) {
            float4 w0 = *(float4*)&wes[kq * 4 + 0][o4];
            float4 w1 = *(float4*)&wes[kq * 4 + 1][o4];
            float4 w2 = *(float4*)&wes[kq * 4 + 2][o4];
            float4 w3 = *(float4*)&wes[kq * 4 + 3][o4];
            #pragma unroll
            for (int r = 0; r < 8; ++r) {
                float4 xv = *(float4*)&xsl[ty * 8 + r][kq * 4];
                acc[r][0] = fmaf(xv.x, w0.x, acc[r][0]);
                acc[r][1] = fmaf(xv.x, w0.y, acc[r][1]);
                acc[r][2] = fmaf(xv.x, w0.z, acc[r][2]);
                acc[r][3] = fmaf(xv.x, w0.w, acc[r][3]);
                acc[r][0] = fmaf(xv.y, w1.x, acc[r][0]);
                acc[r][1] = fmaf(xv.y, w1.y, acc[r][1]);
                acc[r][2] = fmaf(xv.y, w1.z, acc[r][2]);
                acc[r][3] = fmaf(xv.y, w1.w, acc[r][3]);
                acc[r][0] = fmaf(xv.z, w2.x, acc[r][0]);
                acc[r][1] = fmaf(xv.z, w2.y, acc[r][1]);
                acc[r][2] = fmaf(xv.z, w2.z, acc[r][2]);
                acc[r][3] = fmaf(xv.z, w2.w, acc[r][3]);
                acc[r][0] = fmaf(xv.w, w3.x, acc[r][0]);
                acc[r][1] = fmaf(xv.w, w3.y, acc[r][1]);
                acc[r][2] = fmaf(xv.w, w3.z, acc[r][2]);
                acc[r][3] = fmaf(xv.w, w3.w, acc[r][3]);
            }
        }
    }

    // epilogue: bias, predictions (atomic), per-(row,slot) loss
    float cntl = 0.f, rsl = 0.f, wsuml = 0.f;
    #pragma unroll
    for (int r = 0; r < 8; ++r) {
        int li = ty * 8 + r;
        int row = rowid[li];
        bool valid = row >= 0;
        float w = wsl[li];
        float4 tg = make_float4(0.f, 0.f, 0.f, 0.f);
        if (valid) tg = *(const float4*)(tgt + (size_t)row * O_DIM + o4);
        float lpr = 0.f;
        float cf0 = acc[r][0] + be_sh[o4 + 0];
        float cf1 = acc[r][1] + be_sh[o4 + 1];
        float cf2 = acc[r][2] + be_sh[o4 + 2];
        float cf3 = acc[r][3] + be_sh[o4 + 3];
        float d0 = cf0 - tg.x, d1 = cf1 - tg.y, d2 = cf2 - tg.z, d3 = cf3 - tg.w;
        lpr = d0 * d0 + d1 * d1 + d2 * d2 + d3 * d3;
        if (valid) {
            float* pr = out + (size_t)row * O_DIM + o4;
            atomicAdd(pr + 0, w * cf0);
            atomicAdd(pr + 1, w * cf1);
            atomicAdd(pr + 2, w * cf2);
            atomicAdd(pr + 3, w * cf3);
        }
        #pragma unroll
        for (int off = 1; off < 32; off <<= 1)
            lpr += __shfl_xor(lpr, off, 64);
        if (tx == 0 && valid) {
            cntl += 1.f;
            rsl  += -(lpr * (1.0f / 128.0f));
            wsuml += w;
        }
    }
    if (tx == 0) {
        int cp = WS_STATS + (blockIdx.x & 63) * 24;
        if (cntl > 0.f) {
            atomicAdd(&wsf[cp + e], cntl);
            atomicAdd(&wsf[cp + 8 + e], rsl);
            atomicAdd(&wsf[cp + 16 + e], wsuml);
        }
    }
}

// ---------------- K3: finalize stats ----------------
__global__ void final_k(const float* __restrict__ er,
                        const float* __restrict__ ema,
                        const int* __restrict__ pulls,
                        const float* __restrict__ wsf,
                        float* __restrict__ out)
{
    int e = threadIdx.x;
    if (e < E_NUM) {
        double c = 0.0, rs = 0.0, wsum = 0.0;
        for (int cp = 0; cp < 64; ++cp) {
            c    += (double)wsf[WS_STATS + cp * 24 + e];
            rs   += (double)wsf[WS_STATS + cp * 24 + 8 + e];
            wsum += (double)wsf[WS_STATS + cp * 24 + 16 + e];
        }
        double pf = (double)pulls[e];
        double npl = pf + c;
        double ntr = (double)er[e] + rs;
        double sp = npl < 1.0 ? 1.0 : npl;
        double navg = npl > 0.0 ? ntr / sp : 0.0;
        double prob = wsum / (double)B_SZ;
        double nema = 0.99 * (double)ema[e] + 0.01 * prob;
        out[OFF_NP + e] = (float)npl;
        out[OFF_NA + e] = (float)navg;
        out[OFF_NE + e] = (float)nema;
    }
}

extern "C" void kernel_launch(void* const* d_in, const int* in_sizes, int n_in,
                              void* d_out, int out_size, void* d_ws, size_t ws_size,
                              hipStream_t stream) {
    const float* x    = (const float*)d_in[0];
    const float* tgt  = (const float*)d_in[1];
    const float* W1   = (const float*)d_in[2];
    const float* b1   = (const float*)d_in[3];
    const float* W2   = (const float*)d_in[4];
    const float* b2   = (const float*)d_in[5];
    const float* S1   = (const float*)d_in[6];
    const float* sb1  = (const float*)d_in[7];
    const float* S2   = (const float*)d_in[8];
    const float* sb2  = (const float*)d_in[9];
    const float* We   = (const float*)d_in[10];
    const float* be   = (const float*)d_in[11];
    const float* erw  = (const float*)d_in[12];
    const float* ema  = (const float*)d_in[13];
    const int*   pulls = (const int*)d_in[14];
    const int*   tsel  = (const int*)d_in[15];
    float* out = (float*)d_out;
    float* wsf = (float*)d_ws;
    int*   wsi = (int*)d_ws;

    zero_k<<<2048, 256, 0, stream>>>(out, wsf);
    score_k<<<B_SZ / 16, 256, 0, stream>>>(
        x, W1, b1, W2, b2, S1, sb1, S2, sb2, erw, pulls, tsel, out, wsi);
    expert_k<<<E_NUM * 256, 256, 0, stream>>>(x, tgt, We, be, out, wsi, wsf);
    final_k<<<1, 64, 0, stream>>>(erw, ema, pulls, wsf, out);
}

// Round 5
// 220.856 us; speedup vs baseline: 4.4476x; 1.0195x over previous
//
#include <hip/hip_runtime.h>
#include <math.h>

#define B_SZ   16384
#define D_DIM  256
#define E_NUM  8
#define O_DIM  128
#define CTXW   32
#define H1     64

// out layout (f32):
#define OFF_RW   2097152
#define OFF_IDX  2129920
#define OFF_NP   2162688
#define OFF_NA   2162696
#define OFF_NE   2162704

// ws layout:
//  int  wsi[0..7]                 : per-expert counters (list cursors)
//  f32  wsf[256 + copy*24 + j]    : 64 stat copies; j: 0..7 cnt, 8..15 rsum, 16..23 wsum
//  int  wsi[2048 + e*16384 + i]   : per-expert row lists, entry = row*2 + slot
#define WS_STATS 256
#define WS_LIST  2048

// ---------------- K0: zero predictions + counters + stats ----------------
__global__ __launch_bounds__(256) void zero_k(float* out, float* ws) {
    int idx = blockIdx.x * 256 + threadIdx.x;
    if (idx < 524288) ((float4*)out)[idx] = make_float4(0.f, 0.f, 0.f, 0.f);
    if (idx < 512)    ((float4*)ws)[idx]  = make_float4(0.f, 0.f, 0.f, 0.f);
}

// ---------------- K1: encoder + scorer + UCB + top2 + list build (f64) ----------------
// 32 rows/block, 8 rows/wave. Per-row f64 math identical (order) to the
// round-4 version: acc0 starts at b1, acc1 at 0, even k -> acc0, odd -> acc1.
__global__ __launch_bounds__(256) void score_k(
    const float* __restrict__ x,
    const float* __restrict__ W1, const float* __restrict__ b1,
    const float* __restrict__ W2, const float* __restrict__ b2,
    const float* __restrict__ S1, const float* __restrict__ sb1,
    const float* __restrict__ S2, const float* __restrict__ sb2,
    const float* __restrict__ er, const int* __restrict__ pulls,
    const int* __restrict__ tsel,
    float* __restrict__ out, int* __restrict__ wsi)
{
    __shared__ float  xs[32][D_DIM];   // 32 KB
    __shared__ double hs[32][H1];      // 16 KB
    __shared__ double cs[32][CTXW];    // 8 KB
    __shared__ double tss[32][CTXW];   // 8 KB
    __shared__ double ucb[32][E_NUM];  // 2 KB
    __shared__ int    se[64];

    const int t = threadIdx.x, lane = t & 63, wv = t >> 6;
    const int row0 = blockIdx.x * 32;

    // stage 32 rows of x (2048 float4, 8/thread)
    const float4* xsrc = (const float4*)(x + (size_t)row0 * D_DIM);
    #pragma unroll
    for (int i = 0; i < 8; ++i)
        ((float4*)xs)[t + i * 256] = xsrc[t + i * 256];
    __syncthreads();

    // ---- h = relu(x@W1+b1): lane = unit, 8 rows/wave ----
    const int rb = wv * 8;
    {
        double acc0[8], acc1[8];
        double binit = (double)b1[lane];
        #pragma unroll
        for (int r = 0; r < 8; ++r) { acc0[r] = binit; acc1[r] = 0.0; }
        #pragma unroll 4
        for (int d = 0; d < D_DIM; d += 2) {
            double wa = (double)W1[d * H1 + lane];
            double wb = (double)W1[(d + 1) * H1 + lane];
            #pragma unroll
            for (int r = 0; r < 8; ++r) {
                float2 p = *(const float2*)&xs[rb + r][d];
                acc0[r] = fma((double)p.x, wa, acc0[r]);
                acc1[r] = fma((double)p.y, wb, acc1[r]);
            }
        }
        #pragma unroll
        for (int r = 0; r < 8; ++r) {
            double h = acc0[r] + acc1[r];
            hs[rb + r][lane] = h > 0.0 ? h : 0.0;
        }
    }
    __syncthreads();

    // ---- context = tanh(h@W2+b2): unit = lane&31, 4 rows per half-lane ----
    {
        const int unit = lane & 31, half = lane >> 5;
        const int ra = rb + half * 4;
        double c0 = (double)b2[unit], c1 = c0, c2 = c0, c3 = c0;
        #pragma unroll 4
        for (int k = 0; k < H1; ++k) {
            double w2v = (double)W2[k * CTXW + unit];
            c0 = fma(hs[ra + 0][k], w2v, c0);
            c1 = fma(hs[ra + 1][k], w2v, c1);
            c2 = fma(hs[ra + 2][k], w2v, c2);
            c3 = fma(hs[ra + 3][k], w2v, c3);
        }
        cs[ra + 0][unit] = tanh(c0);
        cs[ra + 1][unit] = tanh(c1);
        cs[ra + 2][unit] = tanh(c2);
        cs[ra + 3][unit] = tanh(c3);
    }
    __syncthreads();

    // ---- tmid = relu(context@S1+sb1) ----
    {
        const int unit = lane & 31, half = lane >> 5;
        const int ra = rb + half * 4;
        double a0 = (double)sb1[unit], a1 = a0, a2 = a0, a3 = a0;
        #pragma unroll 4
        for (int k = 0; k < CTXW; ++k) {
            double s1v = (double)S1[k * CTXW + unit];
            a0 = fma(cs[ra + 0][k], s1v, a0);
            a1 = fma(cs[ra + 1][k], s1v, a1);
            a2 = fma(cs[ra + 2][k], s1v, a2);
            a3 = fma(cs[ra + 3][k], s1v, a3);
        }
        tss[ra + 0][unit] = a0 > 0.0 ? a0 : 0.0;
        tss[ra + 1][unit] = a1 > 0.0 ? a1 : 0.0;
        tss[ra + 2][unit] = a2 > 0.0 ? a2 : 0.0;
        tss[ra + 3][unit] = a3 > 0.0 ? a3 : 0.0;
    }
    __syncthreads();

    // ---- scores + UCB: one (row, expert) per thread ----
    {
        const int e = t & 7, r = t >> 3;   // r: 0..31
        double a = (double)sb2[e];
        #pragma unroll 4
        for (int k = 0; k < CTXW; ++k)
            a = fma(tss[r][k], (double)S2[k * E_NUM + e], a);
        double pf = (double)pulls[e];
        double sp = pf < 1.0 ? 1.0 : pf;
        double explo = 0.1 * sqrt(log((double)(*tsel)) / sp);
        double avg = pf > 0.0 ? (double)er[e] / sp : 0.0;
        ucb[r][e] = a + avg + explo;
    }
    __syncthreads();

    // ---- top2 + softmax + emit: threads 0..31, one row each ----
    if (t < 32) {
        double u[E_NUM];
        #pragma unroll
        for (int e = 0; e < E_NUM; ++e) u[e] = ucb[t][e];
        int i0 = 0; double v0 = u[0];
        #pragma unroll
        for (int e = 1; e < E_NUM; ++e) if (u[e] > v0) { v0 = u[e]; i0 = e; }
        int i1 = -1; double v1 = -1.0e300;
        #pragma unroll
        for (int e = 0; e < E_NUM; ++e) {
            if (e == i0) continue;
            if (u[e] > v1) { v1 = u[e]; i1 = e; }
        }
        double exd = exp(v1 - v0);
        double w0 = 1.0 / (1.0 + exd), w1 = exd / (1.0 + exd);
        int row = row0 + t;
        out[OFF_RW  + row * 2]     = (float)w0;
        out[OFF_RW  + row * 2 + 1] = (float)w1;
        out[OFF_IDX + row * 2]     = (float)i0;
        out[OFF_IDX + row * 2 + 1] = (float)i1;
        se[t * 2]     = i0;
        se[t * 2 + 1] = i1;
    }
    __syncthreads();

    // ---- block-aggregated list append: threads 0..7 (one per expert) ----
    if (t < E_NUM) {
        int cntl = 0;
        #pragma unroll
        for (int j = 0; j < 64; ++j) cntl += (se[j] == t);
        if (cntl) {
            int base = atomicAdd(&wsi[t], cntl);
            int k = 0;
            for (int j = 0; j < 64; ++j)
                if (se[j] == t)
                    wsi[WS_LIST + t * B_SZ + base + (k++)] = (row0 + (j >> 1)) * 2 + (j & 1);
        }
    }
}

// ---------------- K2: grouped expert GEMM + losses + stats (32-row tiles) ----------------
__global__ __launch_bounds__(256) void expert_k(
    const float* __restrict__ x, const float* __restrict__ tgt,
    const float* __restrict__ We, const float* __restrict__ be,
    float* out, int* __restrict__ wsi, float* __restrict__ wsf)
{
    const int e = blockIdx.x >> 9, chunk = blockIdx.x & 511;
    const int cnt = wsi[e];
    const int base = chunk * 32;
    if (base >= cnt) return;

    __shared__ float xsl[32][68];      // 8.7 KB
    __shared__ float wes[64][O_DIM];   // 32 KB
    __shared__ int   rowid[32];
    __shared__ float wsl[32];
    __shared__ float be_sh[O_DIM];

    const int t = threadIdx.x;
    if (t < 32) {
        int en = (base + t < cnt) ? wsi[WS_LIST + e * B_SZ + base + t] : -1;
        rowid[t] = (en >= 0) ? (en >> 1) : -1;
        wsl[t]   = (en >= 0) ? out[OFF_RW + en] : 0.f;
    }
    if (t < O_DIM) be_sh[t] = be[e * O_DIM + t];

    float acc[4][4];
    #pragma unroll
    for (int r = 0; r < 4; ++r)
        #pragma unroll
        for (int j = 0; j < 4; ++j) acc[r][j] = 0.f;

    const int tx = t & 31, ty = t >> 5;   // ty 0..7 -> rows ty*4..ty*4+3
    const int o4 = tx * 4;

    for (int k0 = 0; k0 < 4; ++k0) {
        __syncthreads();
        // stage We chunk [64 k][128 o] — contiguous 32 KB
        const float4* wsrc = (const float4*)(We + ((size_t)e * D_DIM + k0 * 64) * O_DIM);
        #pragma unroll
        for (int i = 0; i < 8; ++i)
            ((float4*)wes)[t + i * 256] = wsrc[t + i * 256];
        // stage x rows [32 r][64 k]
        {
            int r = t >> 3, seg = t & 7;
            int rr = rowid[r] < 0 ? 0 : rowid[r];
            const float* xsr = x + (size_t)rr * D_DIM + k0 * 64 + seg * 8;
            *(float4*)&xsl[r][seg * 8]     = *(const float4*)(xsr);
            *(float4*)&xsl[r][seg * 8 + 4] = *(const float4*)(xsr + 4);
        }
        __syncthreads();
        // compute
        #pragma unroll 4
        for (int kq = 0; kq < 16; ++kq) {
            float4 w0 = *(float4*)&wes[kq * 4 + 0][o4];
            float4 w1 = *(float4*)&wes[kq * 4 + 1][o4];
            float4 w2 = *(float4*)&wes[kq * 4 + 2][o4];
            float4 w3 = *(float4*)&wes[kq * 4 + 3][o4];
            #pragma unroll
            for (int r = 0; r < 4; ++r) {
                float4 xv = *(float4*)&xsl[ty * 4 + r][kq * 4];
                acc[r][0] = fmaf(xv.x, w0.x, acc[r][0]);
                acc[r][1] = fmaf(xv.x, w0.y, acc[r][1]);
                acc[r][2] = fmaf(xv.x, w0.z, acc[r][2]);
                acc[r][3] = fmaf(xv.x, w0.w, acc[r][3]);
                acc[r][0] = fmaf(xv.y, w1.x, acc[r][0]);
                acc[r][1] = fmaf(xv.y, w1.y, acc[r][1]);
                acc[r][2] = fmaf(xv.y, w1.z, acc[r][2]);
                acc[r][3] = fmaf(xv.y, w1.w, acc[r][3]);
                acc[r][0] = fmaf(xv.z, w2.x, acc[r][0]);
                acc[r][1] = fmaf(xv.z, w2.y, acc[r][1]);
                acc[r][2] = fmaf(xv.z, w2.z, acc[r][2]);
                acc[r][3] = fmaf(xv.z, w2.w, acc[r][3]);
                acc[r][0] = fmaf(xv.w, w3.x, acc[r][0]);
                acc[r][1] = fmaf(xv.w, w3.y, acc[r][1]);
                acc[r][2] = fmaf(xv.w, w3.z, acc[r][2]);
                acc[r][3] = fmaf(xv.w, w3.w, acc[r][3]);
            }
        }
    }

    // epilogue: bias, predictions (atomic), per-(row,slot) loss
    float cntl = 0.f, rsl = 0.f, wsuml = 0.f;
    #pragma unroll
    for (int r = 0; r < 4; ++r) {
        int li = ty * 4 + r;
        int row = rowid[li];
        bool valid = row >= 0;
        float w = wsl[li];
        float4 tg = make_float4(0.f, 0.f, 0.f, 0.f);
        if (valid) tg = *(const float4*)(tgt + (size_t)row * O_DIM + o4);
        float cf0 = acc[r][0] + be_sh[o4 + 0];
        float cf1 = acc[r][1] + be_sh[o4 + 1];
        float cf2 = acc[r][2] + be_sh[o4 + 2];
        float cf3 = acc[r][3] + be_sh[o4 + 3];
        float d0 = cf0 - tg.x, d1 = cf1 - tg.y, d2 = cf2 - tg.z, d3 = cf3 - tg.w;
        float lpr = d0 * d0 + d1 * d1 + d2 * d2 + d3 * d3;
        if (valid) {
            float* pr = out + (size_t)row * O_DIM + o4;
            atomicAdd(pr + 0, w * cf0);
            atomicAdd(pr + 1, w * cf1);
            atomicAdd(pr + 2, w * cf2);
            atomicAdd(pr + 3, w * cf3);
        }
        #pragma unroll
        for (int off = 1; off < 32; off <<= 1)
            lpr += __shfl_xor(lpr, off, 64);
        if (tx == 0 && valid) {
            cntl += 1.f;
            rsl  += -(lpr * (1.0f / 128.0f));
            wsuml += w;
        }
    }
    if (tx == 0) {
        int cp = WS_STATS + (blockIdx.x & 63) * 24;
        if (cntl > 0.f) {
            atomicAdd(&wsf[cp + e], cntl);
            atomicAdd(&wsf[cp + 8 + e], rsl);
            atomicAdd(&wsf[cp + 16 + e], wsuml);
        }
    }
}

// ---------------- K3: finalize stats ----------------
__global__ void final_k(const float* __restrict__ er,
                        const float* __restrict__ ema,
                        const int* __restrict__ pulls,
                        const float* __restrict__ wsf,
                        float* __restrict__ out)
{
    int e = threadIdx.x;
    if (e < E_NUM) {
        double c = 0.0, rs = 0.0, wsum = 0.0;
        for (int cp = 0; cp < 64; ++cp) {
            c    += (double)wsf[WS_STATS + cp * 24 + e];
            rs   += (double)wsf[WS_STATS + cp * 24 + 8 + e];
            wsum += (double)wsf[WS_STATS + cp * 24 + 16 + e];
        }
        double pf = (double)pulls[e];
        double npl = pf + c;
        double ntr = (double)er[e] + rs;
        double sp = npl < 1.0 ? 1.0 : npl;
        double navg = npl > 0.0 ? ntr / sp : 0.0;
        double prob = wsum / (double)B_SZ;
        double nema = 0.99 * (double)ema[e] + 0.01 * prob;
        out[OFF_NP + e] = (float)npl;
        out[OFF_NA + e] = (float)navg;
        out[OFF_NE + e] = (float)nema;
    }
}

extern "C" void kernel_launch(void* const* d_in, const int* in_sizes, int n_in,
                              void* d_out, int out_size, void* d_ws, size_t ws_size,
                              hipStream_t stream) {
    const float* x    = (const float*)d_in[0];
    const float* tgt  = (const float*)d_in[1];
    const float* W1   = (const float*)d_in[2];
    const float* b1   = (const float*)d_in[3];
    const float* W2   = (const float*)d_in[4];
    const float* b2   = (const float*)d_in[5];
    const float* S1   = (const float*)d_in[6];
    const float* sb1  = (const float*)d_in[7];
    const float* S2   = (const float*)d_in[8];
    const float* sb2  = (const float*)d_in[9];
    const float* We   = (const float*)d_in[10];
    const float* be   = (const float*)d_in[11];
    const float* erw  = (const float*)d_in[12];
    const float* ema  = (const float*)d_in[13];
    const int*   pulls = (const int*)d_in[14];
    const int*   tsel  = (const int*)d_in[15];
    float* out = (float*)d_out;
    float* wsf = (float*)d_ws;
    int*   wsi = (int*)d_ws;

    zero_k<<<2048, 256, 0, stream>>>(out, wsf);
    score_k<<<B_SZ / 32, 256, 0, stream>>>(
        x, W1, b1, W2, b2, S1, sb1, S2, sb2, erw, pulls, tsel, out, wsi);
    expert_k<<<E_NUM * 512, 256, 0, stream>>>(x, tgt, We, be, out, wsi, wsf);
    final_k<<<1, 64, 0, stream>>>(erw, ema, pulls, wsf, out);
}

// Round 8
// 194.865 us; speedup vs baseline: 5.0408x; 1.1334x over previous
//
#include <hip/hip_runtime.h>
#include <math.h>

#define B_SZ   16384
#define D_DIM  256
#define E_NUM  8
#define O_DIM  128
#define CTXW   32
#define H1     64

// out layout (f32):
#define OFF_RW   2097152
#define OFF_IDX  2129920
#define OFF_NP   2162688
#define OFF_NA   2162696
#define OFF_NE   2162704

// ws layout:
//  int  wsi[0..7]    : slot-0 cursors (per expert, grows from front of list)
//  int  wsi[8..15]   : slot-1 cursors (per expert, grows from back of list)
//  f32  wsf[256 + copy*24 + j] : 64 stat copies; j: 0..7 cnt, 8..15 rsum, 16..23 wsum
//  int  wsi[2048 + e*16384 ...]: per-expert arena; slot0 entries at [base..],
//                                slot1 entries at [B_SZ-1-base..] (value = row)
#define WS_STATS 256
#define WS_LIST  2048

// ---------------- K0: zero counters + stats (NOT predictions) ----------------
__global__ __launch_bounds__(256) void zero_k(float* ws) {
    ((float4*)ws)[threadIdx.x]       = make_float4(0.f, 0.f, 0.f, 0.f);
    ((float4*)ws)[threadIdx.x + 256] = make_float4(0.f, 0.f, 0.f, 0.f);
}

// ---------------- K1: encoder + scorer + UCB + top2 + list build (f64) ----------------
__global__ __launch_bounds__(256) void score_k(
    const float* __restrict__ x,
    const float* __restrict__ W1, const float* __restrict__ b1,
    const float* __restrict__ W2, const float* __restrict__ b2,
    const float* __restrict__ S1, const float* __restrict__ sb1,
    const float* __restrict__ S2, const float* __restrict__ sb2,
    const float* __restrict__ er, const int* __restrict__ pulls,
    const int* __restrict__ tsel,
    float* __restrict__ out, int* __restrict__ wsi)
{
    __shared__ float  xs[32][D_DIM];   // 32 KB
    __shared__ double hs[32][H1];      // 16 KB
    __shared__ double cs[32][CTXW];    // 8 KB
    __shared__ double tss[32][CTXW];   // 8 KB
    __shared__ double ucb[32][E_NUM];  // 2 KB
    __shared__ int    se[64];

    const int t = threadIdx.x, lane = t & 63, wv = t >> 6;
    const int row0 = blockIdx.x * 32;

    // stage 32 rows of x (2048 float4, 8/thread)
    const float4* xsrc = (const float4*)(x + (size_t)row0 * D_DIM);
    #pragma unroll
    for (int i = 0; i < 8; ++i)
        ((float4*)xs)[t + i * 256] = xsrc[t + i * 256];
    __syncthreads();

    // ---- h = relu(x@W1+b1): lane = unit, 8 rows/wave ----
    const int rb = wv * 8;
    {
        double acc0[8], acc1[8];
        double binit = (double)b1[lane];
        #pragma unroll
        for (int r = 0; r < 8; ++r) { acc0[r] = binit; acc1[r] = 0.0; }
        #pragma unroll 4
        for (int d = 0; d < D_DIM; d += 2) {
            double wa = (double)W1[d * H1 + lane];
            double wb = (double)W1[(d + 1) * H1 + lane];
            #pragma unroll
            for (int r = 0; r < 8; ++r) {
                float2 p = *(const float2*)&xs[rb + r][d];
                acc0[r] = fma((double)p.x, wa, acc0[r]);
                acc1[r] = fma((double)p.y, wb, acc1[r]);
            }
        }
        #pragma unroll
        for (int r = 0; r < 8; ++r) {
            double h = acc0[r] + acc1[r];
            hs[rb + r][lane] = h > 0.0 ? h : 0.0;
        }
    }
    __syncthreads();

    // ---- context = tanh(h@W2+b2): unit = lane&31, 4 rows per half-lane ----
    {
        const int unit = lane & 31, half = lane >> 5;
        const int ra = rb + half * 4;
        double c0 = (double)b2[unit], c1 = c0, c2 = c0, c3 = c0;
        #pragma unroll 4
        for (int k = 0; k < H1; ++k) {
            double w2v = (double)W2[k * CTXW + unit];
            c0 = fma(hs[ra + 0][k], w2v, c0);
            c1 = fma(hs[ra + 1][k], w2v, c1);
            c2 = fma(hs[ra + 2][k], w2v, c2);
            c3 = fma(hs[ra + 3][k], w2v, c3);
        }
        cs[ra + 0][unit] = tanh(c0);
        cs[ra + 1][unit] = tanh(c1);
        cs[ra + 2][unit] = tanh(c2);
        cs[ra + 3][unit] = tanh(c3);
    }
    __syncthreads();

    // ---- tmid = relu(context@S1+sb1) ----
    {
        const int unit = lane & 31, half = lane >> 5;
        const int ra = rb + half * 4;
        double a0 = (double)sb1[unit], a1 = a0, a2 = a0, a3 = a0;
        #pragma unroll 4
        for (int k = 0; k < CTXW; ++k) {
            double s1v = (double)S1[k * CTXW + unit];
            a0 = fma(cs[ra + 0][k], s1v, a0);
            a1 = fma(cs[ra + 1][k], s1v, a1);
            a2 = fma(cs[ra + 2][k], s1v, a2);
            a3 = fma(cs[ra + 3][k], s1v, a3);
        }
        tss[ra + 0][unit] = a0 > 0.0 ? a0 : 0.0;
        tss[ra + 1][unit] = a1 > 0.0 ? a1 : 0.0;
        tss[ra + 2][unit] = a2 > 0.0 ? a2 : 0.0;
        tss[ra + 3][unit] = a3 > 0.0 ? a3 : 0.0;
    }
    __syncthreads();

    // ---- scores + UCB: one (row, expert) per thread ----
    {
        const int e = t & 7, r = t >> 3;   // r: 0..31
        double a = (double)sb2[e];
        #pragma unroll 4
        for (int k = 0; k < CTXW; ++k)
            a = fma(tss[r][k], (double)S2[k * E_NUM + e], a);
        double pf = (double)pulls[e];
        double sp = pf < 1.0 ? 1.0 : pf;
        double explo = 0.1 * sqrt(log((double)(*tsel)) / sp);
        double avg = pf > 0.0 ? (double)er[e] / sp : 0.0;
        ucb[r][e] = a + avg + explo;
    }
    __syncthreads();

    // ---- top2 + softmax + emit: threads 0..31, one row each ----
    if (t < 32) {
        double u[E_NUM];
        #pragma unroll
        for (int e = 0; e < E_NUM; ++e) u[e] = ucb[t][e];
        int i0 = 0; double v0 = u[0];
        #pragma unroll
        for (int e = 1; e < E_NUM; ++e) if (u[e] > v0) { v0 = u[e]; i0 = e; }
        int i1 = -1; double v1 = -1.0e300;
        #pragma unroll
        for (int e = 0; e < E_NUM; ++e) {
            if (e == i0) continue;
            if (u[e] > v1) { v1 = u[e]; i1 = e; }
        }
        double exd = exp(v1 - v0);
        double w0 = 1.0 / (1.0 + exd), w1 = exd / (1.0 + exd);
        int row = row0 + t;
        out[OFF_RW  + row * 2]     = (float)w0;
        out[OFF_RW  + row * 2 + 1] = (float)w1;
        out[OFF_IDX + row * 2]     = (float)i0;
        out[OFF_IDX + row * 2 + 1] = (float)i1;
        se[t * 2]     = i0;
        se[t * 2 + 1] = i1;
    }
    __syncthreads();

    // ---- block-aggregated list append: 16 threads, one per (expert, slot) ----
    // slot0 entries grow from front of expert arena; slot1 from the back.
    if (t < 16) {
        const int e = t & 7, slot = t >> 3;
        int cntl = 0;
        for (int j = slot; j < 64; j += 2) cntl += (se[j] == e);
        if (cntl) {
            int base = atomicAdd(&wsi[slot * 8 + e], cntl);
            int k = 0;
            if (slot == 0) {
                for (int j = 0; j < 64; j += 2)
                    if (se[j] == e)
                        wsi[WS_LIST + e * B_SZ + base + (k++)] = row0 + (j >> 1);
            } else {
                for (int j = 1; j < 64; j += 2)
                    if (se[j] == e)
                        wsi[WS_LIST + e * B_SZ + (B_SZ - 1 - base - (k++))] = row0 + (j >> 1);
            }
        }
    }
}

// ---------------- K2: grouped expert GEMM + losses + stats, per slot ----------------
// SLOT 0: pred = w*sel (plain store).  SLOT 1: pred += w*sel (plain RMW —
// race-free: each row has exactly one entry per slot; slot0 kernel completes first).
template <int SLOT>
__global__ __launch_bounds__(256) void expert_k(
    const float* __restrict__ x, const float* __restrict__ tgt,
    const float* __restrict__ We, const float* __restrict__ be,
    float* out, int* __restrict__ wsi, float* __restrict__ wsf)
{
    const int e = blockIdx.x >> 9, chunk = blockIdx.x & 511;
    const int cnt = wsi[SLOT * 8 + e];
    const int base = chunk * 32;
    if (base >= cnt) return;

    __shared__ float xsl[32][68];      // 8.7 KB
    __shared__ float wes[64][O_DIM];   // 32 KB
    __shared__ int   rowid[32];
    __shared__ float wsl[32];
    __shared__ float be_sh[O_DIM];

    const int t = threadIdx.x;
    if (t < 32) {
        bool ok = (base + t) < cnt;
        int row = -1;
        if (ok) {
            int idx = (SLOT == 0) ? (base + t) : (B_SZ - 1 - (base + t));
            row = wsi[WS_LIST + e * B_SZ + idx];
        }
        rowid[t] = row;
        wsl[t]   = ok ? out[OFF_RW + row * 2 + SLOT] : 0.f;
    }
    if (t < O_DIM) be_sh[t] = be[e * O_DIM + t];

    float acc[4][4];
    #pragma unroll
    for (int r = 0; r < 4; ++r)
        #pragma unroll
        for (int j = 0; j < 4; ++j) acc[r][j] = 0.f;

    const int tx = t & 31, ty = t >> 5;   // ty 0..7 -> rows ty*4..ty*4+3
    const int o4 = tx * 4;

    for (int k0 = 0; k0 < 4; ++k0) {
        __syncthreads();
        // stage We chunk [64 k][128 o] — contiguous 32 KB
        const float4* wsrc = (const float4*)(We + ((size_t)e * D_DIM + k0 * 64) * O_DIM);
        #pragma unroll
        for (int i = 0; i < 8; ++i)
            ((float4*)wes)[t + i * 256] = wsrc[t + i * 256];
        // stage x rows [32 r][64 k]
        {
            int r = t >> 3, seg = t & 7;
            int rr = rowid[r] < 0 ? 0 : rowid[r];
            const float* xsr = x + (size_t)rr * D_DIM + k0 * 64 + seg * 8;
            *(float4*)&xsl[r][seg * 8]     = *(const float4*)(xsr);
            *(float4*)&xsl[r][seg * 8 + 4] = *(const float4*)(xsr + 4);
        }
        __syncthreads();
        // compute
        #pragma unroll 4
        for (int kq = 0; kq < 16; ++kq) {
            float4 w0 = *(float4*)&wes[kq * 4 + 0][o4];
            float4 w1 = *(float4*)&wes[kq * 4 + 1][o4];
            float4 w2 = *(float4*)&wes[kq * 4 + 2][o4];
            float4 w3 = *(float4*)&wes[kq * 4 + 3][o4];
            #pragma unroll
            for (int r = 0; r < 4; ++r) {
                float4 xv = *(float4*)&xsl[ty * 4 + r][kq * 4];
                acc[r][0] = fmaf(xv.x, w0.x, acc[r][0]);
                acc[r][1] = fmaf(xv.x, w0.y, acc[r][1]);
                acc[r][2] = fmaf(xv.x, w0.z, acc[r][2]);
                acc[r][3] = fmaf(xv.x, w0.w, acc[r][3]);
                acc[r][0] = fmaf(xv.y, w1.x, acc[r][0]);
                acc[r][1] = fmaf(xv.y, w1.y, acc[r][1]);
                acc[r][2] = fmaf(xv.y, w1.z, acc[r][2]);
                acc[r][3] = fmaf(xv.y, w1.w, acc[r][3]);
                acc[r][0] = fmaf(xv.z, w2.x, acc[r][0]);
                acc[r][1] = fmaf(xv.z, w2.y, acc[r][1]);
                acc[r][2] = fmaf(xv.z, w2.z, acc[r][2]);
                acc[r][3] = fmaf(xv.z, w2.w, acc[r][3]);
                acc[r][0] = fmaf(xv.w, w3.x, acc[r][0]);
                acc[r][1] = fmaf(xv.w, w3.y, acc[r][1]);
                acc[r][2] = fmaf(xv.w, w3.z, acc[r][2]);
                acc[r][3] = fmaf(xv.w, w3.w, acc[r][3]);
            }
        }
    }

    // epilogue: bias, predictions (store / RMW-add), per-(row,slot) loss
    float cntl = 0.f, rsl = 0.f, wsuml = 0.f;
    #pragma unroll
    for (int r = 0; r < 4; ++r) {
        int li = ty * 4 + r;
        int row = rowid[li];
        bool valid = row >= 0;
        float w = wsl[li];
        float4 tg = make_float4(0.f, 0.f, 0.f, 0.f);
        if (valid) tg = *(const float4*)(tgt + (size_t)row * O_DIM + o4);
        float cf0 = acc[r][0] + be_sh[o4 + 0];
        float cf1 = acc[r][1] + be_sh[o4 + 1];
        float cf2 = acc[r][2] + be_sh[o4 + 2];
        float cf3 = acc[r][3] + be_sh[o4 + 3];
        float d0 = cf0 - tg.x, d1 = cf1 - tg.y, d2 = cf2 - tg.z, d3 = cf3 - tg.w;
        float lpr = d0 * d0 + d1 * d1 + d2 * d2 + d3 * d3;
        if (valid) {
            float* pr = out + (size_t)row * O_DIM + o4;
            if (SLOT == 0) {
                float4 v = make_float4(w * cf0, w * cf1, w * cf2, w * cf3);
                *(float4*)pr = v;
            } else {
                float4 p = *(const float4*)pr;
                p.x += w * cf0; p.y += w * cf1; p.z += w * cf2; p.w += w * cf3;
                *(float4*)pr = p;
            }
        }
        #pragma unroll
        for (int off = 1; off < 32; off <<= 1)
            lpr += __shfl_xor(lpr, off, 64);
        if (tx == 0 && valid) {
            cntl += 1.f;
            rsl  += -(lpr * (1.0f / 128.0f));
            wsuml += w;
        }
    }
    if (tx == 0) {
        int cp = WS_STATS + (blockIdx.x & 63) * 24;
        if (cntl > 0.f) {
            atomicAdd(&wsf[cp + e], cntl);
            atomicAdd(&wsf[cp + 8 + e], rsl);
            atomicAdd(&wsf[cp + 16 + e], wsuml);
        }
    }
}

// ---------------- K3: finalize stats ----------------
__global__ void final_k(const float* __restrict__ er,
                        const float* __restrict__ ema,
                        const int* __restrict__ pulls,
                        const float* __restrict__ wsf,
                        float* __restrict__ out)
{
    int e = threadIdx.x;
    if (e < E_NUM) {
        double c = 0.0, rs = 0.0, wsum = 0.0;
        for (int cp = 0; cp < 64; ++cp) {
            c    += (double)wsf[WS_STATS + cp * 24 + e];
            rs   += (double)wsf[WS_STATS + cp * 24 + 8 + e];
            wsum += (double)wsf[WS_STATS + cp * 24 + 16 + e];
        }
        double pf = (double)pulls[e];
        double npl = pf + c;
        double ntr = (double)er[e] + rs;
        double sp = npl < 1.0 ? 1.0 : npl;
        double navg = npl > 0.0 ? ntr / sp : 0.0;
        double prob = wsum / (double)B_SZ;
        double nema = 0.99 * (double)ema[e] + 0.01 * prob;
        out[OFF_NP + e] = (float)npl;
        out[OFF_NA + e] = (float)navg;
        out[OFF_NE + e] = (float)nema;
    }
}

extern "C" void kernel_launch(void* const* d_in, const int* in_sizes, int n_in,
                              void* d_out, int out_size, void* d_ws, size_t ws_size,
                              hipStream_t stream) {
    const float* x    = (const float*)d_in[0];
    const float* tgt  = (const float*)d_in[1];
    const float* W1   = (const float*)d_in[2];
    const float* b1   = (const float*)d_in[3];
    const float* W2   = (const float*)d_in[4];
    const float* b2   = (const float*)d_in[5];
    const float* S1   = (const float*)d_in[6];
    const float* sb1  = (const float*)d_in[7];
    const float* S2   = (const float*)d_in[8];
    const float* sb2  = (const float*)d_in[9];
    const float* We   = (const float*)d_in[10];
    const float* be   = (const float*)d_in[11];
    const float* erw  = (const float*)d_in[12];
    const float* ema  = (const float*)d_in[13];
    const int*   pulls = (const int*)d_in[14];
    const int*   tsel  = (const int*)d_in[15];
    float* out = (float*)d_out;
    float* wsf = (float*)d_ws;
    int*   wsi = (int*)d_ws;

    zero_k<<<1, 256, 0, stream>>>(wsf);
    score_k<<<B_SZ / 32, 256, 0, stream>>>(
        x, W1, b1, W2, b2, S1, sb1, S2, sb2, erw, pulls, tsel, out, wsi);
    expert_k<0><<<E_NUM * 512, 256, 0, stream>>>(x, tgt, We, be, out, wsi, wsf);
    expert_k<1><<<E_NUM * 512, 256, 0, stream>>>(x, tgt, We, be, out, wsi, wsf);
    final_k<<<1, 64, 0, stream>>>(erw, ema, pulls, wsf, out);
}